// Round 1
// baseline (712.464 us; speedup 1.0000x reference)
//
#include <hip/hip_runtime.h>

typedef __attribute__((ext_vector_type(8))) short short8;
typedef __attribute__((ext_vector_type(4))) float floatx4;
typedef unsigned int u32;

#define CC 256
#define NN 4096
#define NB 8

static __device__ __forceinline__ float b2f(ushort u) {
    union { unsigned int i; float f; } c;
    c.i = ((unsigned int)u) << 16;
    return c.f;
}

static __device__ __forceinline__ ushort f2bf(float f) {
    union { float f; unsigned int u; } c;
    c.f = f;
    unsigned int u = c.u;
    u += 0x7fffu + ((u >> 16) & 1u);
    return (ushort)(u >> 16);
}

static __device__ __forceinline__ short8 load8(const void* p, size_t idx, bool isbf) {
    if (isbf) {
        return *(const short8*)((const ushort*)p + idx);
    } else {
        const float* f = (const float*)p + idx;
        floatx4 a = *(const floatx4*)f;
        floatx4 b = *(const floatx4*)(f + 4);
        short8 r;
        #pragma unroll
        for (int j = 0; j < 4; j++) {
            ((ushort*)&r)[j]     = f2bf(a[j]);
            ((ushort*)&r)[j + 4] = f2bf(b[j]);
        }
        return r;
    }
}

static __device__ __forceinline__ float loadS(const void* p, size_t idx, bool isbf) {
    return isbf ? b2f(((const ushort*)p)[idx]) : ((const float*)p)[idx];
}

static __device__ __forceinline__ bool detect_bf16(const void* x) {
    const ushort* xu = (const ushort*)x;
    int cnt = 0;
    #pragma unroll
    for (int j = 0; j < 8; j++) {
        ushort u = xu[(size_t)j * 1048576];
        int e = (u >> 7) & 0xFF;
        cnt += ((e >= 100 && e <= 141) || (u & 0x7FFF) == 0) ? 1 : 0;
    }
    return cnt >= 7;
}

// async global -> LDS, 16B per lane; LDS dest must be wave-uniform base
static __device__ __forceinline__ void gll16(const ushort* g, ushort* l) {
    __builtin_amdgcn_global_load_lds(
        (const __attribute__((address_space(1))) u32*)g,
        (__attribute__((address_space(3))) u32*)l, 16, 0, 0);
}

// -------------------------------------------------------------------------
// proj_mfma: one 64x64 tile of Y = W x_b + bias.  (unchanged)
//   mode 0: K -> ws bf16 [bl][N][C]   mode 1: V -> ws bf16 [bl][C][N]
//   mode 2: P -> d_out fp32 [b][C][N] (direct stores)
// grid (NN/64, CC/64, BC), block 256 (4 waves).
// -------------------------------------------------------------------------
__global__ __launch_bounds__(256) void proj_mfma(
    const void* __restrict__ x, const void* __restrict__ W,
    const void* __restrict__ bias, void* __restrict__ dst, int b0, int mode)
{
    __shared__ __align__(16) ushort A_lds[64 * 40];
    __shared__ __align__(16) ushort Bt_lds[64 * 40];
    __shared__ __align__(16) ushort T_lds[64 * 72];

    const bool isbf = detect_bf16(x);
    const int tid  = threadIdx.x;
    const int wave = tid >> 6;
    const int lane = tid & 63;
    const int l16  = lane & 15;
    const int quad = lane >> 4;

    const int n0 = blockIdx.x * 64;
    const int o0 = blockIdx.y * 64;
    const int bl = blockIdx.z;
    const int b  = b0 + bl;

    floatx4 zero4 = {0.f, 0.f, 0.f, 0.f};
    floatx4 acc[4];
    acc[0] = zero4; acc[1] = zero4; acc[2] = zero4; acc[3] = zero4;

    for (int k0 = 0; k0 < CC; k0 += 32) {
        __syncthreads();
        {   // A = W[o0..+64)[k0..+32)
            int row = tid >> 2, c8 = (tid & 3) * 8;
            *(short8*)&A_lds[row * 40 + c8] =
                load8(W, (size_t)(o0 + row) * CC + k0 + c8, isbf);
        }
        {   // Bt = x[k0..+32)[n0..+64) transposed -> [n][c]
            int c = tid >> 3, n8 = (tid & 7) * 8;
            short8 xv = load8(x, ((size_t)b * CC + k0 + c) * NN + n0 + n8, isbf);
            #pragma unroll
            for (int j = 0; j < 8; j++)
                Bt_lds[(n8 + j) * 40 + c] = ((ushort*)&xv)[j];
        }
        __syncthreads();

        short8 af = *(const short8*)&A_lds[(wave * 16 + l16) * 40 + quad * 8];
        #pragma unroll
        for (int t = 0; t < 4; t++) {
            short8 bf = *(const short8*)&Bt_lds[(t * 16 + l16) * 40 + quad * 8];
            acc[t] = __builtin_amdgcn_mfma_f32_16x16x32_bf16(af, bf, acc[t], 0, 0, 0);
        }
    }

    float biasv[4];
    #pragma unroll
    for (int r = 0; r < 4; r++)
        biasv[r] = loadS(bias, (size_t)(o0 + wave * 16 + quad * 4 + r), isbf);

    if (mode == 2) {
        float* po = (float*)dst;
        #pragma unroll
        for (int t = 0; t < 4; t++)
            #pragma unroll
            for (int r = 0; r < 4; r++)
                po[((size_t)b * CC + o0 + wave * 16 + quad * 4 + r) * NN +
                   n0 + t * 16 + l16] = acc[t][r] + biasv[r];
        return;
    }

    __syncthreads();
    if (mode == 0) {
        #pragma unroll
        for (int t = 0; t < 4; t++)
            #pragma unroll
            for (int r = 0; r < 4; r++)
                T_lds[(t * 16 + l16) * 72 + wave * 16 + quad * 4 + r] =
                    f2bf(acc[t][r] + biasv[r]);
    } else {
        #pragma unroll
        for (int t = 0; t < 4; t++)
            #pragma unroll
            for (int r = 0; r < 4; r++)
                T_lds[(wave * 16 + quad * 4 + r) * 72 + t * 16 + l16] =
                    f2bf(acc[t][r] + biasv[r]);
    }
    __syncthreads();

    ushort* dw = (ushort*)dst;
    if (mode == 0) {
        for (int u = tid; u < 512; u += 256) {
            int n = u >> 3, o8 = (u & 7) * 8;
            *(short8*)&dw[((size_t)bl * NN + n0 + n) * CC + o0 + o8] =
                *(const short8*)&T_lds[n * 72 + o8];
        }
    } else {
        for (int u = tid; u < 512; u += 256) {
            int o = u >> 3, n8 = (u & 7) * 8;
            *(short8*)&dw[((size_t)bl * CC + o0 + o) * NN + n0 + n8] =
                *(const short8*)&T_lds[o * 72 + n8];
        }
    }
}

// -------------------------------------------------------------------------
// attn_mfma v2: QBLK=128 (4 waves x 32 q-rows, two 16-row frags each),
// KVBLK=64, double-buffered K/V via global_load_lds (XOR-swizzled source,
// linear dest), swizzled conflict-free ds_read_b128, wave-local P roundtrip
// (no block barrier), 1 barrier per 64-key tile.
// grid (NN/128, BC), block 256 (4 waves), 1 block/CU, 147456 B LDS.
// -------------------------------------------------------------------------
__global__ __launch_bounds__(256, 1) void attn_mfma(
    const void* __restrict__ x,
    const void* __restrict__ Wq, const void* __restrict__ bq,
    const ushort* __restrict__ k_ws, const ushort* __restrict__ v_ws,
    float* __restrict__ out, int b0)
{
    // Pool: 73728 ushorts = 147456 B (max 160 KB/CU; 1 block/CU by grid)
    __shared__ __align__(16) ushort lds[73728];
    // Flash phase: K dbuf [2][64][256] @0, V dbuf [2][256][64] @32768,
    //              P [128][64] @65536
    ushort* Kb = lds;
    ushort* Vb = lds + 32768;
    ushort* Pl = lds + 65536;
    // Phase A (aliases): Qt [128][264] @0, Wc [256][40] @33792, Xt [128][40] @44032
    ushort* Qt = lds;
    ushort* Wc = lds + 33792;
    ushort* Xt = lds + 44032;
    float*  Tf = (float*)lds;   // [128][132] fp32 epilogue (aliases)

    const bool isbf = detect_bf16(x);
    const int tid  = threadIdx.x;
    const int wave = tid >> 6;
    const int lane = tid & 63;
    const int l16  = lane & 15;
    const int quad = lane >> 4;
    const int bl = blockIdx.y;
    const int b  = b0 + bl;
    const int n0 = blockIdx.x * 128;

    floatx4 zero4 = {0.f, 0.f, 0.f, 0.f};

    // ---- Phase A: Q = (x^T Wq^T + bq) * C^-0.5 -> Qt bf16 [128 n][264] ----
    {
        floatx4 qacc[2][16];
        #pragma unroll
        for (int f = 0; f < 2; f++)
            #pragma unroll
            for (int ct = 0; ct < 16; ct++) qacc[f][ct] = zero4;

        #pragma unroll 1
        for (int k0 = 0; k0 < CC; k0 += 32) {
            __syncthreads();
            #pragma unroll
            for (int i = 0; i < 4; i++) {
                int u = tid + i * 256;
                int row = u >> 2, c8 = (u & 3) * 8;
                *(short8*)&Wc[row * 40 + c8] =
                    load8(Wq, (size_t)row * CC + k0 + c8, isbf);
            }
            #pragma unroll
            for (int i = 0; i < 2; i++) {
                int u = tid + i * 256;
                int c = u >> 4, n8 = (u & 15) * 8;
                short8 xv = load8(x, ((size_t)b * CC + k0 + c) * NN + n0 + n8, isbf);
                #pragma unroll
                for (int j = 0; j < 8; j++)
                    Xt[(n8 + j) * 40 + c] = ((ushort*)&xv)[j];
            }
            __syncthreads();

            short8 af0 = *(const short8*)&Xt[(wave * 32 + l16) * 40 + quad * 8];
            short8 af1 = *(const short8*)&Xt[(wave * 32 + 16 + l16) * 40 + quad * 8];
            #pragma unroll
            for (int ct = 0; ct < 16; ct++) {
                short8 bf = *(const short8*)&Wc[(ct * 16 + l16) * 40 + quad * 8];
                qacc[0][ct] = __builtin_amdgcn_mfma_f32_16x16x32_bf16(af0, bf, qacc[0][ct], 0, 0, 0);
                qacc[1][ct] = __builtin_amdgcn_mfma_f32_16x16x32_bf16(af1, bf, qacc[1][ct], 0, 0, 0);
            }
        }

        #pragma unroll
        for (int ct = 0; ct < 16; ct++) {
            float bqv = loadS(bq, (size_t)(ct * 16 + l16), isbf);
            #pragma unroll
            for (int f = 0; f < 2; f++)
                #pragma unroll
                for (int r = 0; r < 4; r++)
                    Qt[(wave * 32 + f * 16 + quad * 4 + r) * 264 + ct * 16 + l16] =
                        f2bf((qacc[f][ct][r] + bqv) * 0.0625f);
        }
    }
    __syncthreads();   // Qt visible (safety), before qf loads
    short8 qf[2][8];
    #pragma unroll
    for (int f = 0; f < 2; f++)
        #pragma unroll
        for (int s = 0; s < 8; s++)
            qf[f][s] = *(const short8*)&Qt[(wave * 32 + f * 16 + l16) * 264 + s * 32 + quad * 8];
    __syncthreads();   // all waves done with Qt before K/V staging overwrites

    // ---- Phase B: flash attention, KVBLK=64, double-buffered staging ----
    const ushort* kp = k_ws + (size_t)bl * NN * CC;   // [n][C]
    const ushort* vp = v_ws + (size_t)bl * CC * NN;   // [C][n]

    auto stage = [&](int it, int buf) {
        ushort* kb = Kb + buf * 16384;
        ushort* vb = Vb + buf * 16384;
        int m0 = it * 64;
        #pragma unroll
        for (int i = 0; i < 8; i++) {
            int c = wave * 8 + i;                       // 1 KB chunk id
            {   // K: rows of 512 B, slot c16 holds global col (c16 ^ row&7)
                int row = c * 2 + (lane >> 5);
                int sw  = (lane & 31) ^ (row & 7);
                gll16(kp + (size_t)(m0 + row) * CC + sw * 8, kb + c * 512);
            }
            {   // V: rows of 128 B (64 keys), same swizzle convention
                int ch = c * 8 + (lane >> 3);
                int sw = (lane & 7) ^ (ch & 7);
                gll16(vp + (size_t)ch * NN + m0 + sw * 8, vb + c * 512);
            }
        }
    };

    floatx4 Oacc[2][16];
    #pragma unroll
    for (int f = 0; f < 2; f++)
        #pragma unroll
        for (int ct = 0; ct < 16; ct++) Oacc[f][ct] = zero4;
    float mrow[2][4], lrow[2][4];
    #pragma unroll
    for (int f = 0; f < 2; f++)
        #pragma unroll
        for (int r = 0; r < 4; r++) { mrow[f][r] = -1e30f; lrow[f][r] = 0.f; }

    stage(0, 0);
    __syncthreads();   // tile 0 staged (vmcnt drained at barrier)

    #pragma unroll 1
    for (int it = 0; it < 64; ++it) {
        int cur = it & 1;
        if (it < 63) stage(it + 1, cur ^ 1);   // async prefetch into other buf

        // QK^T: S[f][t] = Q(frag f) . K(16 keys of t), k=256 over 8 slices
        const ushort* kb = Kb + cur * 16384;
        floatx4 S[2][4];
        #pragma unroll
        for (int f = 0; f < 2; f++)
            #pragma unroll
            for (int t = 0; t < 4; t++) S[f][t] = zero4;
        #pragma unroll
        for (int t = 0; t < 4; t++) {
            int row = t * 16 + l16;
            int rsw = row & 7;
            #pragma unroll
            for (int s = 0; s < 8; s++) {
                short8 kf = *(const short8*)&kb[row * 256 + ((s * 4 + quad) ^ rsw) * 8];
                S[0][t] = __builtin_amdgcn_mfma_f32_16x16x32_bf16(qf[0][s], kf, S[0][t], 0, 0, 0);
                S[1][t] = __builtin_amdgcn_mfma_f32_16x16x32_bf16(qf[1][s], kf, S[1][t], 0, 0, 0);
            }
        }

        // online softmax: rows = (f, quad*4+r), keys = (t, l16)
        float alpha[2][4];
        #pragma unroll
        for (int f = 0; f < 2; f++)
            #pragma unroll
            for (int r = 0; r < 4; r++) {
                float mx = fmaxf(fmaxf(S[f][0][r], S[f][1][r]),
                                 fmaxf(S[f][2][r], S[f][3][r]));
                mx = fmaxf(mx, __shfl_xor(mx, 1, 64));
                mx = fmaxf(mx, __shfl_xor(mx, 2, 64));
                mx = fmaxf(mx, __shfl_xor(mx, 4, 64));
                mx = fmaxf(mx, __shfl_xor(mx, 8, 64));
                float mn = fmaxf(mrow[f][r], mx);
                float al = __expf(mrow[f][r] - mn);
                mrow[f][r] = mn;
                float p0 = __expf(S[f][0][r] - mn);
                float p1 = __expf(S[f][1][r] - mn);
                float p2 = __expf(S[f][2][r] - mn);
                float p3 = __expf(S[f][3][r] - mn);
                S[f][0][r] = p0; S[f][1][r] = p1; S[f][2][r] = p2; S[f][3][r] = p3;
                float rs = (p0 + p1) + (p2 + p3);
                rs += __shfl_xor(rs, 1, 64);
                rs += __shfl_xor(rs, 2, 64);
                rs += __shfl_xor(rs, 4, 64);
                rs += __shfl_xor(rs, 8, 64);
                lrow[f][r] = lrow[f][r] * al + rs;
                alpha[f][r] = al;
            }

        // write P (wave-local rows: only this wave reads them back)
        #pragma unroll
        for (int f = 0; f < 2; f++)
            #pragma unroll
            for (int r = 0; r < 4; r++) {
                int row = wave * 32 + f * 16 + quad * 4 + r;
                int rsw = row & 7;
                int base = row * 64 + (l16 & 7);
                #pragma unroll
                for (int t = 0; t < 4; t++)
                    Pl[base + ((t * 2 + (l16 >> 3)) ^ rsw) * 8] = f2bf(S[f][t][r]);
            }

        // rescale O while P writes drain (VALU overlaps DS pipe)
        #pragma unroll
        for (int f = 0; f < 2; f++)
            #pragma unroll
            for (int ct = 0; ct < 16; ct++)
                #pragma unroll
                for (int r = 0; r < 4; r++)
                    Oacc[f][ct][r] *= alpha[f][r];

        // in-wave fence: DS pipe is in-order per wave; this orders compiler too
        asm volatile("s_waitcnt lgkmcnt(0)" ::: "memory");

        // PV: O[f][ct] += P(frag f) . V(16 ch of ct), m=64 over 2 slices
        const ushort* vb = Vb + cur * 16384;
        int prow0 = wave * 32 + l16;
        int prow1 = prow0 + 16;
        #pragma unroll
        for (int ks = 0; ks < 2; ks++) {
            short8 pf0 = *(const short8*)&Pl[prow0 * 64 + (((ks * 4 + quad) ^ (prow0 & 7)) * 8)];
            short8 pf1 = *(const short8*)&Pl[prow1 * 64 + (((ks * 4 + quad) ^ (prow1 & 7)) * 8)];
            #pragma unroll
            for (int ct = 0; ct < 16; ct++) {
                int ch = ct * 16 + l16;
                short8 vf = *(const short8*)&vb[ch * 64 + (((ks * 4 + quad) ^ (ch & 7)) * 8)];
                Oacc[0][ct] = __builtin_amdgcn_mfma_f32_16x16x32_bf16(pf0, vf, Oacc[0][ct], 0, 0, 0);
                Oacc[1][ct] = __builtin_amdgcn_mfma_f32_16x16x32_bf16(pf1, vf, Oacc[1][ct], 0, 0, 0);
            }
        }
        __syncthreads();   // reads of buf[cur] done; prefetch of cur^1 drained
    }

    // ---- epilogue: out = h/l + P (fp32 RMW), two 128-channel halves ----
    float linv[2][4];
    #pragma unroll
    for (int f = 0; f < 2; f++)
        #pragma unroll
        for (int r = 0; r < 4; r++) linv[f][r] = 1.0f / lrow[f][r];

    #pragma unroll
    for (int h = 0; h < 2; h++) {
        __syncthreads();
        #pragma unroll
        for (int f = 0; f < 2; f++)
            #pragma unroll
            for (int c8 = 0; c8 < 8; c8++) {
                int ct = h * 8 + c8;
                #pragma unroll
                for (int r = 0; r < 4; r++)
                    Tf[(c8 * 16 + l16) * 132 + wave * 32 + f * 16 + quad * 4 + r] =
                        Oacc[f][ct][r] * linv[f][r];
            }
        __syncthreads();
        #pragma unroll
        for (int i = 0; i < 16; i++) {
            int u = tid + i * 256;               // 4096 float4 slots = 128x32
            int row = u >> 5, col4 = (u & 31) * 4;
            size_t gi = ((size_t)b * CC + h * 128 + row) * NN + n0 + col4;
            floatx4 pv = *(const floatx4*)&out[gi];
            floatx4 tv = *(const floatx4*)&Tf[row * 132 + col4];
            pv[0] += tv[0]; pv[1] += tv[1]; pv[2] += tv[2]; pv[3] += tv[3];
            *(floatx4*)&out[gi] = pv;
        }
    }
}

// -------------------------------------------------------------------------
extern "C" void kernel_launch(void* const* d_in, const int* in_sizes, int n_in,
                              void* d_out, int out_size, void* d_ws, size_t ws_size,
                              hipStream_t stream) {
    int xi = 0;
    for (int i = 0; i < n_in; i++)
        if (in_sizes[i] == NB * CC * NN) xi = i;

    const void *x, *Wq, *bq, *Wk, *bk, *Wv, *bv, *Wp, *bp;
    if (xi == 0) {
        x  = d_in[0];
        Wq = d_in[1]; bq = d_in[2];
        Wk = d_in[3]; bk = d_in[4];
        Wv = d_in[5]; bv = d_in[6];
        Wp = d_in[7]; bp = d_in[8];
    } else {
        int wi[4], bi[4], nw = 0, nb = 0;
        for (int i = 0; i < n_in; i++) {
            if (i == xi) continue;
            if (in_sizes[i] == CC * CC) { if (nw < 4) wi[nw++] = i; }
            else                        { if (nb < 4) bi[nb++] = i; }
        }
        x  = d_in[xi];
        Wk = d_in[wi[0]]; Wp = d_in[wi[1]]; Wq = d_in[wi[2]]; Wv = d_in[wi[3]];
        bk = d_in[bi[0]]; bp = d_in[bi[1]]; bq = d_in[bi[2]]; bv = d_in[bi[3]];
    }

    float*  out = (float*)d_out;     // fp32 output
    ushort* ws  = (ushort*)d_ws;

    const size_t tsz_b = (size_t)NN * CC;
    int BC = 8;
    while (BC > 1 && (size_t)BC * tsz_b * 2 * 2 > ws_size) BC >>= 1;
    ushort* k_ws = ws;
    ushort* v_ws = ws + (size_t)BC * tsz_b;

    // P (fp32) for all batches -> d_out
    proj_mfma<<<dim3(NN / 64, CC / 64, NB), dim3(256), 0, stream>>>(
        x, Wp, bp, (void*)out, 0, 2);

    for (int c0 = 0; c0 < NB; c0 += BC) {
        proj_mfma<<<dim3(NN / 64, CC / 64, BC), dim3(256), 0, stream>>>(
            x, Wk, bk, (void*)k_ws, c0, 0);
        proj_mfma<<<dim3(NN / 64, CC / 64, BC), dim3(256), 0, stream>>>(
            x, Wv, bv, (void*)v_ws, c0, 1);
        attn_mfma<<<dim3(NN / 128, BC), dim3(256), 0, stream>>>(
            x, Wq, bq, k_ws, v_ws, out, c0);
    }
}

// Round 2
// 580.770 us; speedup vs baseline: 1.2268x; 1.2268x over previous
//
#include <hip/hip_runtime.h>

typedef __attribute__((ext_vector_type(8))) short short8;
typedef __attribute__((ext_vector_type(4))) float floatx4;
typedef unsigned int u32;

#define CC 256
#define NN 4096
#define NB 8

static __device__ __forceinline__ float b2f(ushort u) {
    union { unsigned int i; float f; } c;
    c.i = ((unsigned int)u) << 16;
    return c.f;
}

static __device__ __forceinline__ ushort f2bf(float f) {
    union { float f; unsigned int u; } c;
    c.f = f;
    unsigned int u = c.u;
    u += 0x7fffu + ((u >> 16) & 1u);
    return (ushort)(u >> 16);
}

static __device__ __forceinline__ short8 load8(const void* p, size_t idx, bool isbf) {
    if (isbf) {
        return *(const short8*)((const ushort*)p + idx);
    } else {
        const float* f = (const float*)p + idx;
        floatx4 a = *(const floatx4*)f;
        floatx4 b = *(const floatx4*)(f + 4);
        short8 r;
        #pragma unroll
        for (int j = 0; j < 4; j++) {
            ((ushort*)&r)[j]     = f2bf(a[j]);
            ((ushort*)&r)[j + 4] = f2bf(b[j]);
        }
        return r;
    }
}

static __device__ __forceinline__ float loadS(const void* p, size_t idx, bool isbf) {
    return isbf ? b2f(((const ushort*)p)[idx]) : ((const float*)p)[idx];
}

static __device__ __forceinline__ bool detect_bf16(const void* x) {
    const ushort* xu = (const ushort*)x;
    int cnt = 0;
    #pragma unroll
    for (int j = 0; j < 8; j++) {
        ushort u = xu[(size_t)j * 1048576];
        int e = (u >> 7) & 0xFF;
        cnt += ((e >= 100 && e <= 141) || (u & 0x7FFF) == 0) ? 1 : 0;
    }
    return cnt >= 7;
}

// async global -> LDS, 16B per lane; LDS dest is wave-uniform base (+lane*16B)
static __device__ __forceinline__ void gll16(const ushort* g, ushort* l) {
    __builtin_amdgcn_global_load_lds(
        (const __attribute__((address_space(1))) u32*)g,
        (__attribute__((address_space(3))) u32*)l, 16, 0, 0);
}

// -------------------------------------------------------------------------
// proj_mfma: one 64x64 tile of Y = W x_b + bias.  (unchanged from v1)
//   mode 0: K -> ws bf16 [bl][N][C]   mode 1: V -> ws bf16 [bl][C][N]
//   mode 2: P -> d_out fp32 [b][C][N] (direct stores)
// grid (NN/64, CC/64, BC), block 256 (4 waves).
// -------------------------------------------------------------------------
__global__ __launch_bounds__(256) void proj_mfma(
    const void* __restrict__ x, const void* __restrict__ W,
    const void* __restrict__ bias, void* __restrict__ dst, int b0, int mode)
{
    __shared__ __align__(16) ushort A_lds[64 * 40];
    __shared__ __align__(16) ushort Bt_lds[64 * 40];
    __shared__ __align__(16) ushort T_lds[64 * 72];

    const bool isbf = detect_bf16(x);
    const int tid  = threadIdx.x;
    const int wave = tid >> 6;
    const int lane = tid & 63;
    const int l16  = lane & 15;
    const int quad = lane >> 4;

    const int n0 = blockIdx.x * 64;
    const int o0 = blockIdx.y * 64;
    const int bl = blockIdx.z;
    const int b  = b0 + bl;

    floatx4 zero4 = {0.f, 0.f, 0.f, 0.f};
    floatx4 acc[4];
    acc[0] = zero4; acc[1] = zero4; acc[2] = zero4; acc[3] = zero4;

    for (int k0 = 0; k0 < CC; k0 += 32) {
        __syncthreads();
        {   // A = W[o0..+64)[k0..+32)
            int row = tid >> 2, c8 = (tid & 3) * 8;
            *(short8*)&A_lds[row * 40 + c8] =
                load8(W, (size_t)(o0 + row) * CC + k0 + c8, isbf);
        }
        {   // Bt = x[k0..+32)[n0..+64) transposed -> [n][c]
            int c = tid >> 3, n8 = (tid & 7) * 8;
            short8 xv = load8(x, ((size_t)b * CC + k0 + c) * NN + n0 + n8, isbf);
            #pragma unroll
            for (int j = 0; j < 8; j++)
                Bt_lds[(n8 + j) * 40 + c] = ((ushort*)&xv)[j];
        }
        __syncthreads();

        short8 af = *(const short8*)&A_lds[(wave * 16 + l16) * 40 + quad * 8];
        #pragma unroll
        for (int t = 0; t < 4; t++) {
            short8 bf = *(const short8*)&Bt_lds[(t * 16 + l16) * 40 + quad * 8];
            acc[t] = __builtin_amdgcn_mfma_f32_16x16x32_bf16(af, bf, acc[t], 0, 0, 0);
        }
    }

    float biasv[4];
    #pragma unroll
    for (int r = 0; r < 4; r++)
        biasv[r] = loadS(bias, (size_t)(o0 + wave * 16 + quad * 4 + r), isbf);

    if (mode == 2) {
        float* po = (float*)dst;
        #pragma unroll
        for (int t = 0; t < 4; t++)
            #pragma unroll
            for (int r = 0; r < 4; r++)
                po[((size_t)b * CC + o0 + wave * 16 + quad * 4 + r) * NN +
                   n0 + t * 16 + l16] = acc[t][r] + biasv[r];
        return;
    }

    __syncthreads();
    if (mode == 0) {
        #pragma unroll
        for (int t = 0; t < 4; t++)
            #pragma unroll
            for (int r = 0; r < 4; r++)
                T_lds[(t * 16 + l16) * 72 + wave * 16 + quad * 4 + r] =
                    f2bf(acc[t][r] + biasv[r]);
    } else {
        #pragma unroll
        for (int t = 0; t < 4; t++)
            #pragma unroll
            for (int r = 0; r < 4; r++)
                T_lds[(wave * 16 + quad * 4 + r) * 72 + t * 16 + l16] =
                    f2bf(acc[t][r] + biasv[r]);
    }
    __syncthreads();

    ushort* dw = (ushort*)dst;
    if (mode == 0) {
        for (int u = tid; u < 512; u += 256) {
            int n = u >> 3, o8 = (u & 7) * 8;
            *(short8*)&dw[((size_t)bl * NN + n0 + n) * CC + o0 + o8] =
                *(const short8*)&T_lds[n * 72 + o8];
        }
    } else {
        for (int u = tid; u < 512; u += 256) {
            int o = u >> 3, n8 = (u & 7) * 8;
            *(short8*)&dw[((size_t)bl * CC + o0 + o) * NN + n0 + n8] =
                *(const short8*)&T_lds[o * 72 + n8];
        }
    }
}

// -------------------------------------------------------------------------
// attn_mfma v3: v1 occupancy structure (QBLK=64, 4 waves, M=16, 72KB LDS
// -> 2 blocks/CU) + v2's conflict-free swizzles + global_load_lds staging
// + KVBLK=64 (2 barriers per 64 keys vs v1's 6) + wave-local P fence.
// grid (NN/64, BC), block 256.
// -------------------------------------------------------------------------
__global__ __launch_bounds__(256) void attn_mfma(
    const void* __restrict__ x,
    const void* __restrict__ Wq, const void* __restrict__ bq,
    const ushort* __restrict__ k_ws, const ushort* __restrict__ v_ws,
    float* __restrict__ out, int b0)
{
    // Pool: 36864 ushorts = 73728 B  (<= 81920 -> 2 blocks/CU)
    __shared__ __align__(16) ushort lds[36864];
    // Flash phase:
    ushort* K_lds  = lds;            // [64][256] swizzled (16B slots ^ row&7)
    ushort* Vt_lds = lds + 16384;    // [256][64] swizzled
    ushort* P_lds  = lds + 32768;    // [64][64]  swizzled, wave-local rows
    // Phase A aliases:
    ushort* Qt_lds = lds;            // [64][264]
    ushort* Wc_lds = lds + 16896;    // [256][40]
    ushort* Xt_lds = lds + 27136;    // [64][40]
    float*  Tf     = (float*)lds;    // [128][68] fp32 epilogue

    const bool isbf = detect_bf16(x);
    const int tid  = threadIdx.x;
    const int wave = tid >> 6;
    const int lane = tid & 63;
    const int l16  = lane & 15;
    const int quad = lane >> 4;
    const int bl = blockIdx.y;
    const int b  = b0 + bl;
    const int n0 = blockIdx.x * 64;

    floatx4 zero4 = {0.f, 0.f, 0.f, 0.f};

    // ---- Phase A: Q = (x^T Wq^T + bq) * C^-0.5, D[n][o]  (v1 verbatim) ----
    {
        floatx4 qacc[16];
        #pragma unroll
        for (int t = 0; t < 16; t++) qacc[t] = zero4;

        for (int k0 = 0; k0 < CC; k0 += 32) {
            __syncthreads();
            #pragma unroll
            for (int i = 0; i < 4; i++) {
                int u = tid + i * 256;
                int row = u >> 2, c8 = (u & 3) * 8;
                *(short8*)&Wc_lds[row * 40 + c8] =
                    load8(Wq, (size_t)row * CC + k0 + c8, isbf);
            }
            {
                int c = tid >> 3, n8 = (tid & 7) * 8;
                short8 xv = load8(x, ((size_t)b * CC + k0 + c) * NN + n0 + n8, isbf);
                #pragma unroll
                for (int j = 0; j < 8; j++)
                    Xt_lds[(n8 + j) * 40 + c] = ((ushort*)&xv)[j];
            }
            __syncthreads();

            short8 af = *(const short8*)&Xt_lds[(wave * 16 + l16) * 40 + quad * 8];
            #pragma unroll
            for (int ct = 0; ct < 16; ct++) {
                short8 bf = *(const short8*)&Wc_lds[(ct * 16 + l16) * 40 + quad * 8];
                qacc[ct] = __builtin_amdgcn_mfma_f32_16x16x32_bf16(af, bf, qacc[ct], 0, 0, 0);
            }
        }

        __syncthreads();
        #pragma unroll
        for (int ct = 0; ct < 16; ct++) {
            float bqv = loadS(bq, (size_t)(ct * 16 + l16), isbf);
            #pragma unroll
            for (int r = 0; r < 4; r++)
                Qt_lds[(wave * 16 + quad * 4 + r) * 264 + ct * 16 + l16] =
                    f2bf((qacc[ct][r] + bqv) * 0.0625f);
        }
    }
    __syncthreads();   // Qt ushort writes -> short8 reads
    short8 qf[8];
    #pragma unroll
    for (int s = 0; s < 8; s++)
        qf[s] = *(const short8*)&Qt_lds[(wave * 16 + l16) * 264 + s * 32 + quad * 8];
    __syncthreads();   // all waves done with Qt before staging overwrites it

    // ---- Phase B: flash attention, KVBLK=64, swizzled LDS ----
    const ushort* kp = k_ws + (size_t)bl * NN * CC;   // [n][C]
    const ushort* vp = v_ws + (size_t)bl * CC * NN;   // [C][n]

    floatx4 Oacc[16];
    #pragma unroll
    for (int t = 0; t < 16; t++) Oacc[t] = zero4;
    float mrow[4], lrow[4];
    #pragma unroll
    for (int r = 0; r < 4; r++) { mrow[r] = -1e30f; lrow[r] = 0.f; }

    #pragma unroll 1
    for (int it = 0; it < 64; ++it) {
        const int m0 = it * 64;
        __syncthreads();   // prev tile's LDS reads complete before overwrite
        // stage K (32 x 1KB chunks) + V (32 x 1KB chunks), 16 chunks/wave.
        // LDS dest linear; global source pre-swizzled so LDS[row][slot p]
        // holds global 16B-block (p ^ (row&7)).
        #pragma unroll
        for (int i = 0; i < 8; i++) {
            int c = wave * 8 + i;
            {   // K: rows of 512 B (2 rows per chunk)
                int row = c * 2 + (lane >> 5);
                int sw  = (lane & 31) ^ (row & 7);
                gll16(kp + (size_t)(m0 + row) * CC + sw * 8, K_lds + c * 512);
            }
            {   // V: rows of 128 B (8 channel-rows per chunk)
                int ch = c * 8 + (lane >> 3);
                int sw = (lane & 7) ^ (ch & 7);
                gll16(vp + (size_t)ch * NN + m0 + sw * 8, Vt_lds + c * 512);
            }
        }
        __syncthreads();   // vmcnt drained at barrier: tile staged

        // QK^T: S[t] = Q . K(16 keys of t), k=256 over 8 slices
        floatx4 S[4];
        S[0] = zero4; S[1] = zero4; S[2] = zero4; S[3] = zero4;
        #pragma unroll
        for (int t = 0; t < 4; t++) {
            int row = t * 16 + l16;
            int rsw = row & 7;
            #pragma unroll
            for (int s = 0; s < 8; s++) {
                short8 kf = *(const short8*)&K_lds[row * 256 + ((s * 4 + quad) ^ rsw) * 8];
                S[t] = __builtin_amdgcn_mfma_f32_16x16x32_bf16(qf[s], kf, S[t], 0, 0, 0);
            }
        }

        // online softmax: rows = quad*4+r, keys = (t, l16)
        float alpha[4];
        #pragma unroll
        for (int r = 0; r < 4; r++) {
            float mx = fmaxf(fmaxf(S[0][r], S[1][r]), fmaxf(S[2][r], S[3][r]));
            mx = fmaxf(mx, __shfl_xor(mx, 1, 64));
            mx = fmaxf(mx, __shfl_xor(mx, 2, 64));
            mx = fmaxf(mx, __shfl_xor(mx, 4, 64));
            mx = fmaxf(mx, __shfl_xor(mx, 8, 64));
            float mn = fmaxf(mrow[r], mx);
            float al = __expf(mrow[r] - mn);
            mrow[r] = mn;
            float p0 = __expf(S[0][r] - mn);
            float p1 = __expf(S[1][r] - mn);
            float p2 = __expf(S[2][r] - mn);
            float p3 = __expf(S[3][r] - mn);
            S[0][r] = p0; S[1][r] = p1; S[2][r] = p2; S[3][r] = p3;
            float rs = (p0 + p1) + (p2 + p3);
            rs += __shfl_xor(rs, 1, 64);
            rs += __shfl_xor(rs, 2, 64);
            rs += __shfl_xor(rs, 4, 64);
            rs += __shfl_xor(rs, 8, 64);
            lrow[r] = lrow[r] * al + rs;
            alpha[r] = al;
        }

        // write P (wave-local rows; swizzled like V)
        #pragma unroll
        for (int r = 0; r < 4; r++) {
            int row = wave * 16 + quad * 4 + r;
            int rsw = row & 7;
            int base = row * 64 + (l16 & 7);
            #pragma unroll
            for (int t = 0; t < 4; t++)
                P_lds[base + ((t * 2 + (l16 >> 3)) ^ rsw) * 8] = f2bf(S[t][r]);
        }

        // rescale O while P writes drain (VALU overlaps DS pipe)
        #pragma unroll
        for (int ct = 0; ct < 16; ct++)
            #pragma unroll
            for (int r = 0; r < 4; r++)
                Oacc[ct][r] *= alpha[r];

        // in-wave fence (DS pipe in-order per wave); pin scheduler (rule 18)
        asm volatile("s_waitcnt lgkmcnt(0)" ::: "memory");
        __builtin_amdgcn_sched_barrier(0);

        // PV: O[ct] += P . V(16 ch of ct), m=64 over 2 slices
        int prow = wave * 16 + l16;
        int psw  = prow & 7;
        #pragma unroll
        for (int ks = 0; ks < 2; ks++) {
            short8 pf = *(const short8*)&P_lds[prow * 64 + ((ks * 4 + quad) ^ psw) * 8];
            #pragma unroll
            for (int ct = 0; ct < 16; ct++) {
                int ch = ct * 16 + l16;
                short8 vf = *(const short8*)&Vt_lds[ch * 64 + ((ks * 4 + quad) ^ (ch & 7)) * 8];
                Oacc[ct] = __builtin_amdgcn_mfma_f32_16x16x32_bf16(pf, vf, Oacc[ct], 0, 0, 0);
            }
        }
    }

    // ---- epilogue: out = h/l + P (fp32 RMW), two 128-channel halves ----
    float linv[4];
    #pragma unroll
    for (int r = 0; r < 4; r++) linv[r] = 1.0f / lrow[r];

    #pragma unroll
    for (int h = 0; h < 2; h++) {
        __syncthreads();   // flash LDS dead (or prev half consumed)
        #pragma unroll
        for (int ct = h * 8; ct < h * 8 + 8; ct++)
            #pragma unroll
            for (int r = 0; r < 4; r++)
                Tf[(ct * 16 + l16 - h * 128) * 68 + wave * 16 + quad * 4 + r] =
                    Oacc[ct][r] * linv[r];
        __syncthreads();
        #pragma unroll
        for (int i = 0; i < 8; i++) {
            int u = tid + i * 256;           // 2048 float4 slots = 128ch x 16
            int row = u >> 4, col4 = (u & 15) * 4;
            size_t gi = ((size_t)b * CC + h * 128 + row) * NN + n0 + col4;
            floatx4 pv = *(const floatx4*)&out[gi];
            floatx4 tv = *(const floatx4*)&Tf[row * 68 + col4];
            pv[0] += tv[0]; pv[1] += tv[1]; pv[2] += tv[2]; pv[3] += tv[3];
            *(floatx4*)&out[gi] = pv;
        }
    }
}

// -------------------------------------------------------------------------
extern "C" void kernel_launch(void* const* d_in, const int* in_sizes, int n_in,
                              void* d_out, int out_size, void* d_ws, size_t ws_size,
                              hipStream_t stream) {
    int xi = 0;
    for (int i = 0; i < n_in; i++)
        if (in_sizes[i] == NB * CC * NN) xi = i;

    const void *x, *Wq, *bq, *Wk, *bk, *Wv, *bv, *Wp, *bp;
    if (xi == 0) {
        x  = d_in[0];
        Wq = d_in[1]; bq = d_in[2];
        Wk = d_in[3]; bk = d_in[4];
        Wv = d_in[5]; bv = d_in[6];
        Wp = d_in[7]; bp = d_in[8];
    } else {
        int wi[4], bi[4], nw = 0, nb = 0;
        for (int i = 0; i < n_in; i++) {
            if (i == xi) continue;
            if (in_sizes[i] == CC * CC) { if (nw < 4) wi[nw++] = i; }
            else                        { if (nb < 4) bi[nb++] = i; }
        }
        x  = d_in[xi];
        Wk = d_in[wi[0]]; Wp = d_in[wi[1]]; Wq = d_in[wi[2]]; Wv = d_in[wi[3]];
        bk = d_in[bi[0]]; bp = d_in[bi[1]]; bq = d_in[bi[2]]; bv = d_in[bi[3]];
    }

    float*  out = (float*)d_out;     // fp32 output
    ushort* ws  = (ushort*)d_ws;

    const size_t tsz_b = (size_t)NN * CC;
    int BC = 8;
    while (BC > 1 && (size_t)BC * tsz_b * 2 * 2 > ws_size) BC >>= 1;
    ushort* k_ws = ws;
    ushort* v_ws = ws + (size_t)BC * tsz_b;

    // P (fp32) for all batches -> d_out
    proj_mfma<<<dim3(NN / 64, CC / 64, NB), dim3(256), 0, stream>>>(
        x, Wp, bp, (void*)out, 0, 2);

    for (int c0 = 0; c0 < NB; c0 += BC) {
        proj_mfma<<<dim3(NN / 64, CC / 64, BC), dim3(256), 0, stream>>>(
            x, Wk, bk, (void*)k_ws, c0, 0);
        proj_mfma<<<dim3(NN / 64, CC / 64, BC), dim3(256), 0, stream>>>(
            x, Wv, bv, (void*)v_ws, c0, 1);
        attn_mfma<<<dim3(NN / 64, BC), dim3(256), 0, stream>>>(
            x, Wq, bq, k_ws, v_ws, out, c0);
    }
}